// Round 14
// baseline (188.275 us; speedup 1.0000x reference)
//
#include <hip/hip_runtime.h>
#include <math.h>

typedef __bf16 bf16;
typedef __bf16 bfrag __attribute__((ext_vector_type(8)));
typedef __bf16 bf4 __attribute__((ext_vector_type(4)));
typedef float f4 __attribute__((ext_vector_type(4)));
typedef float f16v __attribute__((ext_vector_type(16)));
typedef unsigned uint2v __attribute__((ext_vector_type(2)));

#define LOG2E 1.4426950408889634f

#define DEV static __device__ __forceinline__

DEV f4 MFMA(bfrag a, bfrag b, f4 c) {
  return __builtin_amdgcn_mfma_f32_16x16x32_bf16(a, b, c, 0, 0, 0);
}
DEV f16v MFMA32(bfrag a, bfrag b, f16v c) {
  return __builtin_amdgcn_mfma_f32_32x32x16_bf16(a, b, c, 0, 0, 0);
}
DEV float ex2(float x) { return __builtin_amdgcn_exp2f(x); }
DEV uint2v pl32(unsigned a, unsigned b) {
  return __builtin_amdgcn_permlane32_swap(a, b, false, false);
}
DEV void gload_lds16(const bf16* g, bf16* l) {
  __builtin_amdgcn_global_load_lds(
      (const __attribute__((address_space(1))) void*)g,
      (__attribute__((address_space(3))) void*)l, 16, 0, 0);
}

// ---------------- fused setup ----------------
// wfused = [sp_w(256); qw(768); kw(768); vw(768)] rows x 768 cols, bf16.
// bfused = [sp_b; qb; kb; vb] f32. maskBias PRE-SCALED by LOG2E.
__global__ __launch_bounds__(256) void pack_all(
    const float* __restrict__ x, const float* __restrict__ qw, const float* __restrict__ kw,
    const float* __restrict__ vw, const float* __restrict__ ow, const float* __restrict__ sp_w,
    const float* __restrict__ sa_in_w, const float* __restrict__ sa_out_w,
    const float* __restrict__ nw1, const float* __restrict__ mw1, const float* __restrict__ dw1,
    const float* __restrict__ sp_b, const float* __restrict__ qb, const float* __restrict__ kb,
    const float* __restrict__ vb,
    const float* __restrict__ nb1, const float* __restrict__ mb1, const float* __restrict__ db1,
    const int* __restrict__ mask,
    bf16* __restrict__ xb, bf16* __restrict__ wfused, bf16* __restrict__ wob,
    bf16* __restrict__ sainb, bf16* __restrict__ saoutb,
    bf16* __restrict__ w1pack, float* __restrict__ bfused, float* __restrict__ b1pack,
    float* __restrict__ maskBias) {
  int bid = blockIdx.x;
  int tid = threadIdx.x;
  const float* src = nullptr;
  bf16* dst = nullptr;
  int rel = 0;
  if (bid < 3072)      { src = x;       dst = xb;                   rel = bid; }
  else if (bid < 3264) { src = sp_w;    dst = wfused;               rel = bid - 3072; }
  else if (bid < 3840) { src = qw;      dst = wfused + 196608;      rel = bid - 3264; }
  else if (bid < 4416) { src = kw;      dst = wfused + 786432;      rel = bid - 3840; }
  else if (bid < 4992) { src = vw;      dst = wfused + 1376256;     rel = bid - 4416; }
  else if (bid < 5568) { src = ow;      dst = wob;                  rel = bid - 4992; }
  else if (bid < 5760) { src = sa_in_w; dst = sainb;                rel = bid - 5568; }
  else if (bid < 5824) { src = sa_out_w;dst = saoutb;               rel = bid - 5760; }
  else if (bid < 5856) { src = nw1;     dst = w1pack;               rel = bid - 5824; }
  else if (bid < 5888) { src = mw1;     dst = w1pack + 32768;       rel = bid - 5856; }
  else if (bid < 5920) { src = dw1;     dst = w1pack + 2 * 32768;   rel = bid - 5888; }
  else if (bid == 5920) {
    for (int t = tid; t < 640; t += 256) {
      const float* s;
      int j;
      if (t < 64)       { s = sp_b; j = t; }
      else if (t < 256) { s = qb;   j = t - 64; }
      else if (t < 448) { s = kb;   j = t - 256; }
      else              { s = vb;   j = t - 448; }
      reinterpret_cast<float4*>(bfused)[t] = reinterpret_cast<const float4*>(s)[j];
    }
    return;
  } else if (bid == 5921) {
    if (tid < 96) {
      int which = tid / 32, j = tid % 32;
      const float* s = which == 0 ? nb1 : (which == 1 ? mb1 : db1);
      reinterpret_cast<float4*>(b1pack)[tid] = reinterpret_cast<const float4*>(s)[j];
    }
    return;
  } else {
    int idx = (bid - 5922) * 256 + tid;
    int4 m = reinterpret_cast<const int4*>(mask)[idx];
    float4 o;
    o.x = m.x > 0 ? 0.f : -1e9f * LOG2E;
    o.y = m.y > 0 ? 0.f : -1e9f * LOG2E;
    o.z = m.z > 0 ? 0.f : -1e9f * LOG2E;
    o.w = m.w > 0 ? 0.f : -1e9f * LOG2E;
    reinterpret_cast<float4*>(maskBias)[idx] = o;
    return;
  }
  int i = rel * 256 + tid;
  float4 v = reinterpret_cast<const float4*>(src)[i];
  bf4 o;
  o[0] = (bf16)v.x; o[1] = (bf16)v.y; o[2] = (bf16)v.z; o[3] = (bf16)v.w;
  reinterpret_cast<bf4*>(dst)[i] = o;
}

// ---------------- GEMM 64x64 tile ----------------
template<int OUTF32, int RELU>
__global__ __launch_bounds__(256) void gemm_nt(
    const bf16* __restrict__ A, int lda,
    const bf16* __restrict__ W, int ldw,
    const float* __restrict__ bias,
    void* __restrict__ C, int ldc,
    int N64, int K) {
  int lane = threadIdx.x & 63;
  int w = threadIdx.x >> 6;
  int lrow = lane & 15, lgrp = lane >> 4;
  int tn = blockIdx.x % N64, tm = blockIdx.x / N64;
  int m0 = tm * 64 + (w >> 1) * 32;
  int n0 = tn * 64 + (w & 1) * 32;
  const bf16* Ab = A + (size_t)m0 * lda + lgrp * 8;
  const bf16* Wb = W + (size_t)n0 * ldw + lgrp * 8;
  f4 acc[2][2] = {};
  for (int k0 = 0; k0 < K; k0 += 32) {
    bfrag a0 = *(const bfrag*)(Ab + (size_t)lrow * lda + k0);
    bfrag a1 = *(const bfrag*)(Ab + (size_t)(lrow + 16) * lda + k0);
    bfrag b0 = *(const bfrag*)(Wb + (size_t)lrow * ldw + k0);
    bfrag b1 = *(const bfrag*)(Wb + (size_t)(lrow + 16) * ldw + k0);
    acc[0][0] = MFMA(a0, b0, acc[0][0]);
    acc[0][1] = MFMA(a0, b1, acc[0][1]);
    acc[1][0] = MFMA(a1, b0, acc[1][0]);
    acc[1][1] = MFMA(a1, b1, acc[1][1]);
  }
#pragma unroll
  for (int mi = 0; mi < 2; mi++)
#pragma unroll
    for (int nj = 0; nj < 2; nj++) {
      int col = n0 + nj * 16 + lrow;
      float bv = bias[col];
      int rowb = m0 + mi * 16 + lgrp * 4;
#pragma unroll
      for (int i = 0; i < 4; i++) {
        float v = acc[mi][nj][i] + bv;
        if (RELU) v = fmaxf(v, 0.f);
        if (OUTF32)
          ((float*)C)[(size_t)(rowb + i) * ldc + col] = v;
        else
          ((bf16*)C)[(size_t)(rowb + i) * ldc + col] = (bf16)v;
      }
    }
}

// ---------------- GEMM 128x128 tile, global_load_lds + swizzled LDS, 2-phase dbuf ----------
template<int OUTF32>
__global__ __launch_bounds__(256, 2) void gemm_big(
    const bf16* __restrict__ A,
    const bf16* __restrict__ W,
    const float* __restrict__ bias,
    void* __restrict__ C, int ldc,
    int N128, int K) {
  __shared__ char smem[65536];
  int lane = threadIdx.x & 63;
  int w = threadIdx.x >> 6;
  int lrow = lane & 15, lgrp = lane >> 4;
  int tn = blockIdx.x % N128, tm = blockIdx.x / N128;
  int m0 = tm * 128, n0 = tn * 128;

  int srow = lane >> 3;
  int sslot = (lane & 7) ^ srow;

  auto stage = [&](int bufb, int k0) {
#pragma unroll
    for (int j = 0; j < 4; j++) {
      int rb = (w * 4 + j) * 8 + srow;
      gload_lds16(A + (size_t)(m0 + rb) * K + k0 + sslot * 8,
                  (bf16*)(smem + bufb + (w * 4 + j) * 1024));
      gload_lds16(W + (size_t)(n0 + rb) * K + k0 + sslot * 8,
                  (bf16*)(smem + bufb + 16384 + (w * 4 + j) * 1024));
    }
  };

  f4 acc[4][4] = {};
  int swz = (lrow & 7) << 4;
  int mbase = (w >> 1) * 64, nbase = (w & 1) * 64;

  stage(0, 0);
  __syncthreads();
  int buf = 0;
  int nt = K / 64;
  for (int t = 0; t < nt; t++) {
    int nbuf = buf ^ 32768;
    if (t + 1 < nt) stage(nbuf, (t + 1) * 64);
    const char* As = smem + buf;
    const char* Ws = smem + buf + 16384;
#pragma unroll
    for (int kb = 0; kb < 128; kb += 64) {
      bfrag a[4], b[4];
#pragma unroll
      for (int i = 0; i < 4; i++) {
        a[i] = *(const bfrag*)(As + (mbase + i * 16 + lrow) * 128 + ((kb + lgrp * 16) ^ swz));
        b[i] = *(const bfrag*)(Ws + (nbase + i * 16 + lrow) * 128 + ((kb + lgrp * 16) ^ swz));
      }
#pragma unroll
      for (int mi = 0; mi < 4; mi++)
#pragma unroll
        for (int nj = 0; nj < 4; nj++)
          acc[mi][nj] = MFMA(a[mi], b[nj], acc[mi][nj]);
    }
    __syncthreads();
    buf = nbuf;
  }

#pragma unroll
  for (int mi = 0; mi < 4; mi++)
#pragma unroll
    for (int nj = 0; nj < 4; nj++) {
      int col = n0 + nbase + nj * 16 + lrow;
      float bv = bias[col];
      int rowb = m0 + mbase + mi * 16 + lgrp * 4;
#pragma unroll
      for (int i = 0; i < 4; i++) {
        float v = acc[mi][nj][i] + bv;
        if (OUTF32)
          ((float*)C)[(size_t)(rowb + i) * ldc + col] = v;
        else
          ((bf16*)C)[(size_t)(rowb + i) * ldc + col] = (bf16)v;
      }
    }
}

// ---------------- V transpose: Vt[b][h][d][s] = V[b][s][coff + h*64 + d] ----------------
__global__ __launch_bounds__(256) void vtrans(const bf16* __restrict__ V, int rs, int coff,
                                              bf16* __restrict__ Vt, int H, int S) {
  int nst = S / 64;
  int st = blockIdx.x % nst;
  int h = (blockIdx.x / nst) % H;
  int b = blockIdx.x / (nst * H);
  __shared__ bf16 tile[64][72];
  int t = threadIdx.x;
  int r = t >> 2, c = t & 3;
  const bf16* src = V + ((size_t)b * S + st * 64 + r) * rs + coff + h * 64 + c * 16;
  bfrag v0 = *(const bfrag*)(src);
  bfrag v1 = *(const bfrag*)(src + 8);
  *(bfrag*)&tile[r][c * 16] = v0;
  *(bfrag*)&tile[r][c * 16 + 8] = v1;
  __syncthreads();
  bf16* dst = Vt + (((size_t)b * H + h) * 64 + r) * S + st * 64 + c * 16;
  bfrag o0, o1;
#pragma unroll
  for (int j = 0; j < 8; j++) {
    o0[j] = tile[c * 16 + j][r];
    o1[j] = tile[c * 16 + 8 + j][r];
  }
  *(bfrag*)dst = o0;
  *(bfrag*)(dst + 8) = o1;
}

// ---------------- flash attention v11: 8-wave blocks (256 q), shared K/V staging ---------
// Block = 512 threads = 8 waves, each owning 32 queries; all share one 32KB K/V dbuf.
// Staging per wave per tile: 1 gload_lds for K (rows w*8..w*8+8) + 1 for V — amortized
// over 256 queries. No-max exp2 softmax; permlane P-pack; XCD-bijective block swizzle.
template<int SPLIT, int PARTIAL>
__global__ __launch_bounds__(512) void flash11_k(
    const bf16* __restrict__ Q, const bf16* __restrict__ Kp, int rs,
    const bf16* __restrict__ Vt, const float* __restrict__ bias,
    bf16* __restrict__ O, int ors,
    bf16* __restrict__ Opart, float* __restrict__ Lpart,
    int H, int S, float scale, int Bc) {
  int nqt = S / 256;
  int nwg8 = (gridDim.x >> 3);
  int bid0 = blockIdx.x;
  int bid = (bid0 & 7) * nwg8 + (bid0 >> 3);   // XCD-chunked bijection (grid%8==0)
  int qt = bid % nqt;
  int hh = (bid / nqt) % H;
  int b = (bid / (nqt * H)) % Bc;
  int sp = bid / (nqt * H * Bc);
  int lane = threadIdx.x & 63, w = threadIdx.x >> 6;   // w in 0..7
  int l31 = lane & 31, hf = lane >> 5;
  int q0 = qt * 256 + w * 32;
  const int kchunk = S / SPLIT;
  int k_beg = sp * kchunk;
  int swzl = (l31 & 7) << 4;

  const bf16* Qb = Q + ((size_t)b * S + q0 + l31) * rs + hh * 64 + hf * 8;
  bfrag qf[4];
#pragma unroll
  for (int c = 0; c < 4; c++) qf[c] = *(const bfrag*)(Qb + 16 * c);

  const bf16* gK0 = Kp + ((size_t)b * S + k_beg) * rs + hh * 64;
  const bf16* gV0 = Vt + (((size_t)b * H + hh) * 64) * (size_t)S + k_beg;
  const float* biasb = bias + (size_t)b * S + k_beg;

  __shared__ bf16 KT[2][4096];
  __shared__ bf16 VT[2][4096];

  f16v acc0, acc1;
#pragma unroll
  for (int r = 0; r < 16; r++) { acc0[r] = 0.f; acc1[r] = 0.f; }
  float lrun = 0.f;

  int srow = lane >> 3;
  int sel = ((lane & 7) ^ srow) * 8;
  int rK = w * 8 + srow;   // wave w stages K/V rows w*8..w*8+8

  auto stage = [&](int bb, int trel) {
    const bf16* gK = gK0 + (size_t)trel * 64 * rs;
    const bf16* gV = gV0 + trel * 64;
    gload_lds16(gK + (size_t)rK * rs + sel, KT[bb] + w * 512);
    gload_lds16(gV + (size_t)rK * S + sel, VT[bb] + w * 512);
  };

  stage(0, 0);
  __syncthreads();

  const int nt = kchunk / 64;
  int buf = 0;
  for (int t = 0; t < nt; t++) {
    if (t + 1 < nt) stage(buf ^ 1, t + 1);

    // bias loads off the critical path
    f4 blo[4], bhi[4];
#pragma unroll
    for (int g = 0; g < 4; g++) {
      blo[g] = *(const f4*)(biasb + t * 64 + g * 8 + hf * 4);
      bhi[g] = *(const f4*)(biasb + t * 64 + 32 + g * 8 + hf * 4);
    }

    const char* KTb = (const char*)KT[buf];
    const char* VTb = (const char*)VT[buf];

    f16v s_lo, s_hi;
#pragma unroll
    for (int r = 0; r < 16; r++) { s_lo[r] = 0.f; s_hi[r] = 0.f; }
    __builtin_amdgcn_s_setprio(1);
#pragma unroll
    for (int c = 0; c < 4; c++) {
      int colb = 32 * c + 16 * hf;
      bfrag klo = *(const bfrag*)(KTb + l31 * 128 + (colb ^ swzl));
      bfrag khi = *(const bfrag*)(KTb + (32 + l31) * 128 + (colb ^ swzl));
      s_lo = MFMA32(klo, qf[c], s_lo);
      s_hi = MFMA32(khi, qf[c], s_hi);
    }
    __builtin_amdgcn_s_setprio(0);

    // p = exp2(s * scale + bias)  (no max tracking; masked keys underflow to 0)
#pragma unroll
    for (int r = 0; r < 16; r++) {
      s_lo[r] = ex2(s_lo[r] * scale + blo[r >> 2][r & 3]);
      s_hi[r] = ex2(s_hi[r] * scale + bhi[r >> 2][r & 3]);
    }
    float rsum = s_lo[0] + s_hi[0];
#pragma unroll
    for (int r = 1; r < 16; r++) rsum += s_lo[r] + s_hi[r];
    rsum += __shfl_xor(rsum, 32);
    lrun += rsum;

    // P fragments: cvt_pk to bf16 pairs + permlane32_swap (verified R11)
    bfrag pb[4];
#pragma unroll
    for (int cc = 0; cc < 4; cc++) {
      const f16v& sv = (cc < 2) ? s_lo : s_hi;
      int rb = (cc & 1) * 8;
      unsigned lo0, lo1, hi0, hi1;
      asm("v_cvt_pk_bf16_f32 %0, %1, %2" : "=v"(lo0) : "v"(sv[rb + 0]), "v"(sv[rb + 1]));
      asm("v_cvt_pk_bf16_f32 %0, %1, %2" : "=v"(lo1) : "v"(sv[rb + 2]), "v"(sv[rb + 3]));
      asm("v_cvt_pk_bf16_f32 %0, %1, %2" : "=v"(hi0) : "v"(sv[rb + 4]), "v"(sv[rb + 5]));
      asm("v_cvt_pk_bf16_f32 %0, %1, %2" : "=v"(hi1) : "v"(sv[rb + 6]), "v"(sv[rb + 7]));
      uint2v e0 = pl32(lo0, hi0);
      uint2v e1 = pl32(lo1, hi1);
      union { bfrag v; unsigned u[4]; } pu;
      pu.u[0] = e0[0]; pu.u[1] = e1[0]; pu.u[2] = e0[1]; pu.u[3] = e1[1];
      pb[cc] = pu.v;
    }

    __builtin_amdgcn_s_setprio(1);
#pragma unroll
    for (int c = 0; c < 4; c++) {
      int colb = 32 * c + 16 * hf;
      bfrag v0 = *(const bfrag*)(VTb + l31 * 128 + (colb ^ swzl));
      bfrag v1 = *(const bfrag*)(VTb + (32 + l31) * 128 + (colb ^ swzl));
      acc0 = MFMA32(v0, pb[c], acc0);
      acc1 = MFMA32(v1, pb[c], acc1);
    }
    __builtin_amdgcn_s_setprio(0);

    __syncthreads();
    buf ^= 1;
  }

  int q = q0 + l31;
  if (PARTIAL) {
    bf16* op = Opart + ((((size_t)sp * Bc + b) * H + hh) * S + q) * 64 + hf * 4;
#pragma unroll
    for (int g = 0; g < 4; g++) {
      bf4 v0, v1;
#pragma unroll
      for (int i = 0; i < 4; i++) {
        v0[i] = (bf16)acc0[4 * g + i];
        v1[i] = (bf16)acc1[4 * g + i];
      }
      *(bf4*)(op + g * 8) = v0;
      *(bf4*)(op + 32 + g * 8) = v1;
    }
    if (hf == 0)
      Lpart[(((size_t)sp * Bc + b) * H + hh) * S + q] = lrun;
  } else {
    float inv = 1.f / lrun;
    bf16* Ob = O + ((size_t)b * S + q) * ors + hh * 64 + hf * 4;
#pragma unroll
    for (int g = 0; g < 4; g++) {
      bf4 o0, o1;
#pragma unroll
      for (int i = 0; i < 4; i++) {
        o0[i] = (bf16)(acc0[4 * g + i] * inv);
        o1[i] = (bf16)(acc1[4 * g + i] * inv);
      }
      *(bf4*)(Ob + g * 8) = o0;
      *(bf4*)(Ob + 32 + g * 8) = o1;
    }
  }
}

// ---------------- combine split-K flash partials (fixed m: plain sums, bf16 partials) ----
__global__ __launch_bounds__(256) void flash_comb(
    const bf16* __restrict__ Opart, const float* __restrict__ L,
    bf16* __restrict__ O, int ors, int Hh, int S, int Bc, int nsplit) {
  int idx = blockIdx.x * 256 + threadIdx.x;
  int d4 = idx & 15;
  int q = (idx >> 4) % S;
  int hh = ((idx >> 4) / S) % Hh;
  int b = (idx >> 4) / (S * Hh);
  size_t rowstride = (size_t)Bc * Hh * S;
  size_t rbase = ((size_t)b * Hh + hh) * S + q;
  float lsum = 0.f;
  f4 o = {0.f, 0.f, 0.f, 0.f};
  for (int sp = 0; sp < nsplit; sp++) {
    lsum += L[sp * rowstride + rbase];
    bf4 a = *(const bf4*)(Opart + (sp * rowstride + rbase) * 64 + d4 * 4);
#pragma unroll
    for (int i = 0; i < 4; i++) o[i] += (float)a[i];
  }
  float inv = 1.f / lsum;
  bf4 obv;
#pragma unroll
  for (int i = 0; i < 4; i++) obv[i] = (bf16)(o[i] * inv);
  *(bf4*)(O + ((size_t)b * S + q) * ors + hh * 64 + d4 * 4) = obv;
}

// ---------------- survival epilogue (writes exp2-domain bias) ----------------
__global__ __launch_bounds__(256) void surv_k(
    const bf16* __restrict__ hid,
    const float* __restrict__ nw2, const float* __restrict__ nb2,
    const float* __restrict__ mw2, const float* __restrict__ mb2,
    const float* __restrict__ dw2, const float* __restrict__ db2,
    const float* __restrict__ maskBias, float* __restrict__ biasMain) {
  int w = threadIdx.x >> 6, lane = threadIdx.x & 63;
  int row = blockIdx.x * 4 + w;
  const bf16* hr = hid + (size_t)row * 384;
  const float* W2[3] = {nw2, mw2, dw2};
  float outs[3];
#pragma unroll
  for (int t = 0; t < 3; t++) {
    float acc = (float)hr[t * 128 + lane] * W2[t][lane] +
                (float)hr[t * 128 + 64 + lane] * W2[t][64 + lane];
    for (int msk = 1; msk < 64; msk <<= 1) acc += __shfl_xor(acc, msk);
    outs[t] = acc;
  }
  if (lane == 0) {
    float xn = outs[0] + nb2[0];
    float n = (xn > 20.f) ? xn : log1pf(__expf(xn));
    float mu = 1.f / (1.f + __expf(-(outs[1] + mb2[0])));
    float delta = fmaxf(outs[2] + db2[0], 0.f);
    float surv = logf(n + 1e-8f) + logf(mu + 1e-8f) - delta;
    biasMain[row] = 0.1f * LOG2E * surv + maskBias[row];
  }
}

extern "C" void kernel_launch(void* const* d_in, const int* in_sizes, int n_in,
                              void* d_out, int out_size, void* d_ws, size_t ws_size,
                              hipStream_t stream) {
  const int B = 2, S = 2048, H = 768, I = 256;
  const int NH = 12, SNH = 4;
  const int M = B * S;  // 4096
  const int NF = 2560;  // fused front-GEMM width: 256 (h0) + 3*768 (QKV)
  const float SC = 0.125f * LOG2E;

  const float* x = (const float*)d_in[0];
  const int* mask = (const int*)d_in[1];
  const float* qw = (const float*)d_in[2];
  const float* qb = (const float*)d_in[3];
  const float* kw = (const float*)d_in[4];
  const float* kb = (const float*)d_in[5];
  const float* vw = (const float*)d_in[6];
  const float* vb = (const float*)d_in[7];
  const float* ow = (const float*)d_in[8];
  const float* ob = (const float*)d_in[9];
  const float* sp_w = (const float*)d_in[10];
  const float* sp_b = (const float*)d_in[11];
  const float* sa_in_w = (const float*)d_in[12];
  const float* sa_in_b = (const float*)d_in[13];
  const float* sa_out_w = (const float*)d_in[14];
  const float* sa_out_b = (const float*)d_in[15];
  const float* nw1 = (const float*)d_in[16];
  const float* nb1 = (const float*)d_in[17];
  const float* nw2 = (const float*)d_in[18];
  const float* nb2 = (const float*)d_in[19];
  const float* mw1 = (const float*)d_in[20];
  const float* mb1 = (const float*)d_in[21];
  const float* mw2 = (const float*)d_in[22];
  const float* mb2 = (const float*)d_in[23];
  const float* dw1 = (const float*)d_in[24];
  const float* db1 = (const float*)d_in[25];
  const float* dw2 = (const float*)d_in[26];
  const float* db2 = (const float*)d_in[27];

  char* ws = (char*)d_ws;
  size_t off = 0;
  auto alloc = [&](size_t bytes) -> void* {
    void* p = ws + off;
    off += (bytes + 255) & ~(size_t)255;
    return p;
  };

  // persistent
  bf16* xb = (bf16*)alloc((size_t)M * H * 2);
  bf16* wfused = (bf16*)alloc((size_t)NF * H * 2);
  float* bfused = (float*)alloc((size_t)NF * 4);
  bf16* wob = (bf16*)alloc((size_t)H * H * 2);
  bf16* sainb = (bf16*)alloc((size_t)(3 * I) * I * 2);
  bf16* saoutb = (bf16*)alloc((size_t)I * I * 2);
  bf16* w1pack = (bf16*)alloc((size_t)384 * 256 * 2);
  float* b1pack = (float*)alloc((size_t)384 * 4);
  float* maskBias = (float*)alloc((size_t)M * 4);
  float* biasMain = (float*)alloc((size_t)M * 4);
  bf16* Cfused = (bf16*)alloc((size_t)M * NF * 2);  // [h0 | Q | K | V], ld=NF

  const int SPM = 4, SPS = 8;
  size_t offMark = off;
  // phase A (scorer)
  bf16* qkv_s = (bf16*)alloc((size_t)M * (3 * I) * 2);
  bf16* vt_s = (bf16*)alloc((size_t)B * SNH * 64 * S * 2);
  bf16* attn_s = (bf16*)alloc((size_t)M * I * 2);
  bf16* h1 = (bf16*)alloc((size_t)M * I * 2);
  bf16* hid = (bf16*)alloc((size_t)M * 384 * 2);
  bf16* Opart_s = (bf16*)alloc((size_t)SPS * B * SNH * S * 64 * 2);
  float* L_s = (float*)alloc((size_t)SPS * B * SNH * S * 4);
  size_t endA = off;
  // phase B (main) overlays phase A
  off = offMark;
  bf16* vt_m = (bf16*)alloc((size_t)B * NH * 64 * S * 2);
  bf16* attn_m = (bf16*)alloc((size_t)M * H * 2);
  bf16* Opart_m = (bf16*)alloc((size_t)SPM * B * NH * S * 64 * 2);
  float* L_m = (float*)alloc((size_t)SPM * B * NH * S * 4);
  size_t endB = off;
  size_t need = endA > endB ? endA : endB;
  bool split_ok = ws_size >= need;
  (void)in_sizes; (void)n_in; (void)out_size;

  pack_all<<<5926, 256, 0, stream>>>(x, qw, kw, vw, ow, sp_w, sa_in_w, sa_out_w, nw1, mw1, dw1,
                                     sp_b, qb, kb, vb, nb1, mb1, db1, mask,
                                     xb, wfused, wob, sainb, saoutb, w1pack, bfused, b1pack,
                                     maskBias);

  // fused front GEMM: Cfused = xb @ [sp_w; qw; kw; vw]^T + bfused
  gemm_big<0><<<(M / 128) * (NF / 128), 256, 0, stream>>>(xb, wfused, bfused, Cfused, NF,
                                                          NF / 128, H);

  // ---- scorer branch (h0 = Cfused[:, 0:256], lda=NF) ----
  gemm_nt<0, 0><<<(M / 64) * ((3 * I) / 64), 256, 0, stream>>>(Cfused, NF, sainb, I, sa_in_b,
                                                               qkv_s, 3 * I, (3 * I) / 64, I);
  vtrans<<<B * SNH * (S / 64), 256, 0, stream>>>(qkv_s, 3 * I, 2 * I, vt_s, SNH, S);
  if (split_ok) {
    flash11_k<SPS, 1><<<SPS * B * SNH * (S / 256), 512, 0, stream>>>(
        qkv_s, qkv_s + I, 3 * I, vt_s, maskBias, nullptr, 0, Opart_s, L_s, SNH, S, SC, B);
    flash_comb<<<(B * SNH * S * 16) / 256, 256, 0, stream>>>(Opart_s, L_s, attn_s, I, SNH, S,
                                                             B, SPS);
  } else {
    flash11_k<1, 0><<<B * SNH * (S / 256), 512, 0, stream>>>(
        qkv_s, qkv_s + I, 3 * I, vt_s, maskBias, attn_s, I, nullptr, nullptr, SNH, S, SC, B);
  }
  gemm_nt<0, 0><<<(M / 64) * (I / 64), 256, 0, stream>>>(attn_s, I, saoutb, I, sa_out_b, h1, I,
                                                         I / 64, I);
  gemm_nt<0, 1><<<(M / 64) * (384 / 64), 256, 0, stream>>>(h1, I, w1pack, I, b1pack, hid, 384,
                                                           384 / 64, I);
  surv_k<<<M / 4, 256, 0, stream>>>(hid, nw2, nb2, mw2, mb2, dw2, db2, maskBias, biasMain);

  // ---- main branch (Q/K/V = Cfused cols 256/1024/1792, rs=NF) ----
  vtrans<<<B * NH * (S / 64), 256, 0, stream>>>(Cfused, NF, 1792, vt_m, NH, S);
  if (split_ok) {
    flash11_k<SPM, 1><<<SPM * B * NH * (S / 256), 512, 0, stream>>>(
        Cfused + 256, Cfused + 1024, NF, vt_m, biasMain, nullptr, 0, Opart_m, L_m, NH, S, SC,
        B);
    flash_comb<<<(B * NH * S * 16) / 256, 256, 0, stream>>>(Opart_m, L_m, attn_m, H, NH, S, B,
                                                            SPM);
  } else {
    flash11_k<1, 0><<<B * NH * (S / 256), 512, 0, stream>>>(
        Cfused + 256, Cfused + 1024, NF, vt_m, biasMain, attn_m, H, nullptr, nullptr, NH, S,
        SC, B);
  }
  gemm_big<1><<<(M / 128) * (H / 128), 256, 0, stream>>>(attn_m, wob, ob, d_out, H,
                                                         H / 128, H);
}

// Round 15
// 171.385 us; speedup vs baseline: 1.0985x; 1.0985x over previous
//
#include <hip/hip_runtime.h>
#include <math.h>

typedef __bf16 bf16;
typedef __bf16 bfrag __attribute__((ext_vector_type(8)));
typedef __bf16 bf4 __attribute__((ext_vector_type(4)));
typedef float f4 __attribute__((ext_vector_type(4)));
typedef float f16v __attribute__((ext_vector_type(16)));
typedef unsigned uint2v __attribute__((ext_vector_type(2)));

#define LOG2E 1.4426950408889634f

#define DEV static __device__ __forceinline__

DEV f4 MFMA(bfrag a, bfrag b, f4 c) {
  return __builtin_amdgcn_mfma_f32_16x16x32_bf16(a, b, c, 0, 0, 0);
}
DEV f16v MFMA32(bfrag a, bfrag b, f16v c) {
  return __builtin_amdgcn_mfma_f32_32x32x16_bf16(a, b, c, 0, 0, 0);
}
DEV float ex2(float x) { return __builtin_amdgcn_exp2f(x); }
DEV uint2v pl32(unsigned a, unsigned b) {
  return __builtin_amdgcn_permlane32_swap(a, b, false, false);
}
DEV void gload_lds16(const bf16* g, bf16* l) {
  __builtin_amdgcn_global_load_lds(
      (const __attribute__((address_space(1))) void*)g,
      (__attribute__((address_space(3))) void*)l, 16, 0, 0);
}
DEV void gload_lds4(const float* g, float* l) {
  __builtin_amdgcn_global_load_lds(
      (const __attribute__((address_space(1))) void*)g,
      (__attribute__((address_space(3))) void*)l, 4, 0, 0);
}

// ---------------- fused setup ----------------
__global__ __launch_bounds__(256) void pack_all(
    const float* __restrict__ x, const float* __restrict__ qw, const float* __restrict__ kw,
    const float* __restrict__ vw, const float* __restrict__ ow, const float* __restrict__ sp_w,
    const float* __restrict__ sa_in_w, const float* __restrict__ sa_out_w,
    const float* __restrict__ nw1, const float* __restrict__ mw1, const float* __restrict__ dw1,
    const float* __restrict__ sp_b, const float* __restrict__ qb, const float* __restrict__ kb,
    const float* __restrict__ vb,
    const float* __restrict__ nb1, const float* __restrict__ mb1, const float* __restrict__ db1,
    const int* __restrict__ mask,
    bf16* __restrict__ xb, bf16* __restrict__ wfused, bf16* __restrict__ wob,
    bf16* __restrict__ sainb, bf16* __restrict__ saoutb,
    bf16* __restrict__ w1pack, float* __restrict__ bfused, float* __restrict__ b1pack,
    float* __restrict__ maskBias) {
  int bid = blockIdx.x;
  int tid = threadIdx.x;
  const float* src = nullptr;
  bf16* dst = nullptr;
  int rel = 0;
  if (bid < 3072)      { src = x;       dst = xb;                   rel = bid; }
  else if (bid < 3264) { src = sp_w;    dst = wfused;               rel = bid - 3072; }
  else if (bid < 3840) { src = qw;      dst = wfused + 196608;      rel = bid - 3264; }
  else if (bid < 4416) { src = kw;      dst = wfused + 786432;      rel = bid - 3840; }
  else if (bid < 4992) { src = vw;      dst = wfused + 1376256;     rel = bid - 4416; }
  else if (bid < 5568) { src = ow;      dst = wob;                  rel = bid - 4992; }
  else if (bid < 5760) { src = sa_in_w; dst = sainb;                rel = bid - 5568; }
  else if (bid < 5824) { src = sa_out_w;dst = saoutb;               rel = bid - 5760; }
  else if (bid < 5856) { src = nw1;     dst = w1pack;               rel = bid - 5824; }
  else if (bid < 5888) { src = mw1;     dst = w1pack + 32768;       rel = bid - 5856; }
  else if (bid < 5920) { src = dw1;     dst = w1pack + 2 * 32768;   rel = bid - 5888; }
  else if (bid == 5920) {
    for (int t = tid; t < 640; t += 256) {
      const float* s;
      int j;
      if (t < 64)       { s = sp_b; j = t; }
      else if (t < 256) { s = qb;   j = t - 64; }
      else if (t < 448) { s = kb;   j = t - 256; }
      else              { s = vb;   j = t - 448; }
      reinterpret_cast<float4*>(bfused)[t] = reinterpret_cast<const float4*>(s)[j];
    }
    return;
  } else if (bid == 5921) {
    if (tid < 96) {
      int which = tid / 32, j = tid % 32;
      const float* s = which == 0 ? nb1 : (which == 1 ? mb1 : db1);
      reinterpret_cast<float4*>(b1pack)[tid] = reinterpret_cast<const float4*>(s)[j];
    }
    return;
  } else {
    int idx = (bid - 5922) * 256 + tid;
    int4 m = reinterpret_cast<const int4*>(mask)[idx];
    float4 o;
    o.x = m.x > 0 ? 0.f : -1e9f * LOG2E;
    o.y = m.y > 0 ? 0.f : -1e9f * LOG2E;
    o.z = m.z > 0 ? 0.f : -1e9f * LOG2E;
    o.w = m.w > 0 ? 0.f : -1e9f * LOG2E;
    reinterpret_cast<float4*>(maskBias)[idx] = o;
    return;
  }
  int i = rel * 256 + tid;
  float4 v = reinterpret_cast<const float4*>(src)[i];
  bf4 o;
  o[0] = (bf16)v.x; o[1] = (bf16)v.y; o[2] = (bf16)v.z; o[3] = (bf16)v.w;
  reinterpret_cast<bf4*>(dst)[i] = o;
}

// ---------------- GEMM 64x64 tile ----------------
template<int OUTF32, int RELU>
__global__ __launch_bounds__(256) void gemm_nt(
    const bf16* __restrict__ A, int lda,
    const bf16* __restrict__ W, int ldw,
    const float* __restrict__ bias,
    void* __restrict__ C, int ldc,
    int N64, int K) {
  int lane = threadIdx.x & 63;
  int w = threadIdx.x >> 6;
  int lrow = lane & 15, lgrp = lane >> 4;
  int tn = blockIdx.x % N64, tm = blockIdx.x / N64;
  int m0 = tm * 64 + (w >> 1) * 32;
  int n0 = tn * 64 + (w & 1) * 32;
  const bf16* Ab = A + (size_t)m0 * lda + lgrp * 8;
  const bf16* Wb = W + (size_t)n0 * ldw + lgrp * 8;
  f4 acc[2][2] = {};
  for (int k0 = 0; k0 < K; k0 += 32) {
    bfrag a0 = *(const bfrag*)(Ab + (size_t)lrow * lda + k0);
    bfrag a1 = *(const bfrag*)(Ab + (size_t)(lrow + 16) * lda + k0);
    bfrag b0 = *(const bfrag*)(Wb + (size_t)lrow * ldw + k0);
    bfrag b1 = *(const bfrag*)(Wb + (size_t)(lrow + 16) * ldw + k0);
    acc[0][0] = MFMA(a0, b0, acc[0][0]);
    acc[0][1] = MFMA(a0, b1, acc[0][1]);
    acc[1][0] = MFMA(a1, b0, acc[1][0]);
    acc[1][1] = MFMA(a1, b1, acc[1][1]);
  }
#pragma unroll
  for (int mi = 0; mi < 2; mi++)
#pragma unroll
    for (int nj = 0; nj < 2; nj++) {
      int col = n0 + nj * 16 + lrow;
      float bv = bias[col];
      int rowb = m0 + mi * 16 + lgrp * 4;
#pragma unroll
      for (int i = 0; i < 4; i++) {
        float v = acc[mi][nj][i] + bv;
        if (RELU) v = fmaxf(v, 0.f);
        if (OUTF32)
          ((float*)C)[(size_t)(rowb + i) * ldc + col] = v;
        else
          ((bf16*)C)[(size_t)(rowb + i) * ldc + col] = (bf16)v;
      }
    }
}

// ---------------- GEMM 128x128 tile, global_load_lds + swizzled LDS, 2-phase dbuf ----------
template<int OUTF32>
__global__ __launch_bounds__(256, 2) void gemm_big(
    const bf16* __restrict__ A,
    const bf16* __restrict__ W,
    const float* __restrict__ bias,
    void* __restrict__ C, int ldc,
    int N128, int K) {
  __shared__ char smem[65536];
  int lane = threadIdx.x & 63;
  int w = threadIdx.x >> 6;
  int lrow = lane & 15, lgrp = lane >> 4;
  int tn = blockIdx.x % N128, tm = blockIdx.x / N128;
  int m0 = tm * 128, n0 = tn * 128;

  int srow = lane >> 3;
  int sslot = (lane & 7) ^ srow;

  auto stage = [&](int bufb, int k0) {
#pragma unroll
    for (int j = 0; j < 4; j++) {
      int rb = (w * 4 + j) * 8 + srow;
      gload_lds16(A + (size_t)(m0 + rb) * K + k0 + sslot * 8,
                  (bf16*)(smem + bufb + (w * 4 + j) * 1024));
      gload_lds16(W + (size_t)(n0 + rb) * K + k0 + sslot * 8,
                  (bf16*)(smem + bufb + 16384 + (w * 4 + j) * 1024));
    }
  };

  f4 acc[4][4] = {};
  int swz = (lrow & 7) << 4;
  int mbase = (w >> 1) * 64, nbase = (w & 1) * 64;

  stage(0, 0);
  __syncthreads();
  int buf = 0;
  int nt = K / 64;
  for (int t = 0; t < nt; t++) {
    int nbuf = buf ^ 32768;
    if (t + 1 < nt) stage(nbuf, (t + 1) * 64);
    const char* As = smem + buf;
    const char* Ws = smem + buf + 16384;
#pragma unroll
    for (int kb = 0; kb < 128; kb += 64) {
      bfrag a[4], b[4];
#pragma unroll
      for (int i = 0; i < 4; i++) {
        a[i] = *(const bfrag*)(As + (mbase + i * 16 + lrow) * 128 + ((kb + lgrp * 16) ^ swz));
        b[i] = *(const bfrag*)(Ws + (nbase + i * 16 + lrow) * 128 + ((kb + lgrp * 16) ^ swz));
      }
#pragma unroll
      for (int mi = 0; mi < 4; mi++)
#pragma unroll
        for (int nj = 0; nj < 4; nj++)
          acc[mi][nj] = MFMA(a[mi], b[nj], acc[mi][nj]);
    }
    __syncthreads();
    buf = nbuf;
  }

#pragma unroll
  for (int mi = 0; mi < 4; mi++)
#pragma unroll
    for (int nj = 0; nj < 4; nj++) {
      int col = n0 + nbase + nj * 16 + lrow;
      float bv = bias[col];
      int rowb = m0 + mbase + mi * 16 + lgrp * 4;
#pragma unroll
      for (int i = 0; i < 4; i++) {
        float v = acc[mi][nj][i] + bv;
        if (OUTF32)
          ((float*)C)[(size_t)(rowb + i) * ldc + col] = v;
        else
          ((bf16*)C)[(size_t)(rowb + i) * ldc + col] = (bf16)v;
      }
    }
}

// ---------------- V transpose ----------------
__global__ __launch_bounds__(256) void vtrans(const bf16* __restrict__ V, int rs, int coff,
                                              bf16* __restrict__ Vt, int H, int S) {
  int nst = S / 64;
  int st = blockIdx.x % nst;
  int h = (blockIdx.x / nst) % H;
  int b = blockIdx.x / (nst * H);
  __shared__ bf16 tile[64][72];
  int t = threadIdx.x;
  int r = t >> 2, c = t & 3;
  const bf16* src = V + ((size_t)b * S + st * 64 + r) * rs + coff + h * 64 + c * 16;
  bfrag v0 = *(const bfrag*)(src);
  bfrag v1 = *(const bfrag*)(src + 8);
  *(bfrag*)&tile[r][c * 16] = v0;
  *(bfrag*)&tile[r][c * 16 + 8] = v1;
  __syncthreads();
  bf16* dst = Vt + (((size_t)b * H + h) * 64 + r) * S + st * 64 + c * 16;
  bfrag o0, o1;
#pragma unroll
  for (int j = 0; j < 8; j++) {
    o0[j] = tile[c * 16 + j][r];
    o1[j] = tile[c * 16 + 8 + j][r];
  }
  *(bfrag*)dst = o0;
  *(bfrag*)(dst + 8) = o1;
}

// ---------------- flash attention v12: counted-vmcnt 3-deep pipeline ----------------
// flash10 geometry (4 waves, 128 q) but: 3 staging buffers (K,V,bias all via gload_lds;
// 5 loads/wave/stage), raw s_barrier (NO vmcnt drain), manual s_waitcnt vmcnt(5) so the
// next-tile (and next-next) stage loads stay in flight ACROSS the barrier (T3/T4).
template<int SPLIT, int PARTIAL>
__global__ __launch_bounds__(256) void flash12_k(
    const bf16* __restrict__ Q, const bf16* __restrict__ Kp, int rs,
    const bf16* __restrict__ Vt, const float* __restrict__ bias,
    bf16* __restrict__ O, int ors,
    bf16* __restrict__ Opart, float* __restrict__ Lpart,
    int H, int S, float scale, int Bc) {
  int nqt = S / 128;
  int nwg8 = (gridDim.x >> 3);
  int bid0 = blockIdx.x;
  int bid = (bid0 & 7) * nwg8 + (bid0 >> 3);   // XCD-chunked bijection (grid%8==0)
  int qt = bid % nqt;
  int hh = (bid / nqt) % H;
  int b = (bid / (nqt * H)) % Bc;
  int sp = bid / (nqt * H * Bc);
  int lane = threadIdx.x & 63, w = threadIdx.x >> 6;
  int l31 = lane & 31, hf = lane >> 5;
  int q0 = qt * 128 + w * 32;
  const int kchunk = S / SPLIT;
  int k_beg = sp * kchunk;
  int swzl = (l31 & 7) << 4;

  const bf16* Qb = Q + ((size_t)b * S + q0 + l31) * rs + hh * 64 + hf * 8;
  bfrag qf[4];
#pragma unroll
  for (int c = 0; c < 4; c++) qf[c] = *(const bfrag*)(Qb + 16 * c);

  const bf16* gK0 = Kp + ((size_t)b * S + k_beg) * rs + hh * 64;
  const bf16* gV0 = Vt + (((size_t)b * H + hh) * 64) * (size_t)S + k_beg;
  const float* biasb = bias + (size_t)b * S + k_beg;

  __shared__ bf16 KT[3][4096];
  __shared__ bf16 VT[3][4096];
  __shared__ float BL[3][64];

  f16v acc0, acc1;
#pragma unroll
  for (int r = 0; r < 16; r++) { acc0[r] = 0.f; acc1[r] = 0.f; }
  float lrun = 0.f;

  int srow = lane >> 3;
  int sel = ((lane & 7) ^ srow) * 8;
  int r0 = (w * 2) * 8 + srow;
  int r1 = (w * 2 + 1) * 8 + srow;

  // 5 gload_lds per wave per stage (uniform vmcnt accounting)
  auto stage = [&](int bb, int trel) {
    const bf16* gK = gK0 + (size_t)trel * 64 * rs;
    const bf16* gV = gV0 + trel * 64;
    gload_lds16(gK + (size_t)r0 * rs + sel, KT[bb] + (w * 2) * 512);
    gload_lds16(gK + (size_t)r1 * rs + sel, KT[bb] + (w * 2 + 1) * 512);
    gload_lds16(gV + (size_t)r0 * S + sel, VT[bb] + (w * 2) * 512);
    gload_lds16(gV + (size_t)r1 * S + sel, VT[bb] + (w * 2 + 1) * 512);
    gload_lds4(biasb + trel * 64 + lane, BL[bb]);   // all waves write same 256B (benign)
  };

  const int nt = kchunk / 64;
  stage(0, 0);
  if (nt > 1) stage(1, 1);

  int buf = 0;
  for (int t = 0; t < nt; t++) {
    // all stages except the newest have landed; loads stay in flight across the barrier
    if (t + 1 < nt) asm volatile("s_waitcnt vmcnt(5)" ::: "memory");
    else            asm volatile("s_waitcnt vmcnt(0)" ::: "memory");
    __builtin_amdgcn_s_barrier();
    __builtin_amdgcn_sched_barrier(0);
    if (t + 2 < nt) stage(buf == 0 ? 2 : buf - 1, t + 2);  // (t+2)%3

    const char* KTb = (const char*)KT[buf];
    const char* VTb = (const char*)VT[buf];
    const float* BLb = BL[buf];

    f4 blo[4], bhi[4];
#pragma unroll
    for (int g = 0; g < 4; g++) {
      blo[g] = *(const f4*)(BLb + g * 8 + hf * 4);
      bhi[g] = *(const f4*)(BLb + 32 + g * 8 + hf * 4);
    }

    f16v s_lo, s_hi;
#pragma unroll
    for (int r = 0; r < 16; r++) { s_lo[r] = 0.f; s_hi[r] = 0.f; }
    __builtin_amdgcn_s_setprio(1);
#pragma unroll
    for (int c = 0; c < 4; c++) {
      int colb = 32 * c + 16 * hf;
      bfrag klo = *(const bfrag*)(KTb + l31 * 128 + (colb ^ swzl));
      bfrag khi = *(const bfrag*)(KTb + (32 + l31) * 128 + (colb ^ swzl));
      s_lo = MFMA32(klo, qf[c], s_lo);
      s_hi = MFMA32(khi, qf[c], s_hi);
    }
    __builtin_amdgcn_s_setprio(0);

    // p = exp2(s * scale + bias)  (no max tracking; masked keys underflow to 0)
#pragma unroll
    for (int r = 0; r < 16; r++) {
      s_lo[r] = ex2(s_lo[r] * scale + blo[r >> 2][r & 3]);
      s_hi[r] = ex2(s_hi[r] * scale + bhi[r >> 2][r & 3]);
    }
    float rsum = s_lo[0] + s_hi[0];
#pragma unroll
    for (int r = 1; r < 16; r++) rsum += s_lo[r] + s_hi[r];
    rsum += __shfl_xor(rsum, 32);
    lrun += rsum;

    bfrag pb[4];
#pragma unroll
    for (int cc = 0; cc < 4; cc++) {
      const f16v& sv = (cc < 2) ? s_lo : s_hi;
      int rb = (cc & 1) * 8;
      unsigned lo0, lo1, hi0, hi1;
      asm("v_cvt_pk_bf16_f32 %0, %1, %2" : "=v"(lo0) : "v"(sv[rb + 0]), "v"(sv[rb + 1]));
      asm("v_cvt_pk_bf16_f32 %0, %1, %2" : "=v"(lo1) : "v"(sv[rb + 2]), "v"(sv[rb + 3]));
      asm("v_cvt_pk_bf16_f32 %0, %1, %2" : "=v"(hi0) : "v"(sv[rb + 4]), "v"(sv[rb + 5]));
      asm("v_cvt_pk_bf16_f32 %0, %1, %2" : "=v"(hi1) : "v"(sv[rb + 6]), "v"(sv[rb + 7]));
      uint2v e0 = pl32(lo0, hi0);
      uint2v e1 = pl32(lo1, hi1);
      union { bfrag v; unsigned u[4]; } pu;
      pu.u[0] = e0[0]; pu.u[1] = e1[0]; pu.u[2] = e0[1]; pu.u[3] = e1[1];
      pb[cc] = pu.v;
    }

    __builtin_amdgcn_s_setprio(1);
#pragma unroll
    for (int c = 0; c < 4; c++) {
      int colb = 32 * c + 16 * hf;
      bfrag v0 = *(const bfrag*)(VTb + l31 * 128 + (colb ^ swzl));
      bfrag v1 = *(const bfrag*)(VTb + (32 + l31) * 128 + (colb ^ swzl));
      acc0 = MFMA32(v0, pb[c], acc0);
      acc1 = MFMA32(v1, pb[c], acc1);
    }
    __builtin_amdgcn_s_setprio(0);

    buf = (buf == 2) ? 0 : buf + 1;
  }

  int q = q0 + l31;
  if (PARTIAL) {
    bf16* op = Opart + ((((size_t)sp * Bc + b) * H + hh) * S + q) * 64 + hf * 4;
#pragma unroll
    for (int g = 0; g < 4; g++) {
      bf4 v0, v1;
#pragma unroll
      for (int i = 0; i < 4; i++) {
        v0[i] = (bf16)acc0[4 * g + i];
        v1[i] = (bf16)acc1[4 * g + i];
      }
      *(bf4*)(op + g * 8) = v0;
      *(bf4*)(op + 32 + g * 8) = v1;
    }
    if (hf == 0)
      Lpart[(((size_t)sp * Bc + b) * H + hh) * S + q] = lrun;
  } else {
    float inv = 1.f / lrun;
    bf16* Ob = O + ((size_t)b * S + q) * ors + hh * 64 + hf * 4;
#pragma unroll
    for (int g = 0; g < 4; g++) {
      bf4 o0, o1;
#pragma unroll
      for (int i = 0; i < 4; i++) {
        o0[i] = (bf16)(acc0[4 * g + i] * inv);
        o1[i] = (bf16)(acc1[4 * g + i] * inv);
      }
      *(bf4*)(Ob + g * 8) = o0;
      *(bf4*)(Ob + 32 + g * 8) = o1;
    }
  }
}

// ---------------- combine split-K flash partials (fixed m: plain sums, bf16 partials) ----
__global__ __launch_bounds__(256) void flash_comb(
    const bf16* __restrict__ Opart, const float* __restrict__ L,
    bf16* __restrict__ O, int ors, int Hh, int S, int Bc, int nsplit) {
  int idx = blockIdx.x * 256 + threadIdx.x;
  int d4 = idx & 15;
  int q = (idx >> 4) % S;
  int hh = ((idx >> 4) / S) % Hh;
  int b = (idx >> 4) / (S * Hh);
  size_t rowstride = (size_t)Bc * Hh * S;
  size_t rbase = ((size_t)b * Hh + hh) * S + q;
  float lsum = 0.f;
  f4 o = {0.f, 0.f, 0.f, 0.f};
  for (int sp = 0; sp < nsplit; sp++) {
    lsum += L[sp * rowstride + rbase];
    bf4 a = *(const bf4*)(Opart + (sp * rowstride + rbase) * 64 + d4 * 4);
#pragma unroll
    for (int i = 0; i < 4; i++) o[i] += (float)a[i];
  }
  float inv = 1.f / lsum;
  bf4 obv;
#pragma unroll
  for (int i = 0; i < 4; i++) obv[i] = (bf16)(o[i] * inv);
  *(bf4*)(O + ((size_t)b * S + q) * ors + hh * 64 + d4 * 4) = obv;
}

// ---------------- survival epilogue (writes exp2-domain bias) ----------------
__global__ __launch_bounds__(256) void surv_k(
    const bf16* __restrict__ hid,
    const float* __restrict__ nw2, const float* __restrict__ nb2,
    const float* __restrict__ mw2, const float* __restrict__ mb2,
    const float* __restrict__ dw2, const float* __restrict__ db2,
    const float* __restrict__ maskBias, float* __restrict__ biasMain) {
  int w = threadIdx.x >> 6, lane = threadIdx.x & 63;
  int row = blockIdx.x * 4 + w;
  const bf16* hr = hid + (size_t)row * 384;
  const float* W2[3] = {nw2, mw2, dw2};
  float outs[3];
#pragma unroll
  for (int t = 0; t < 3; t++) {
    float acc = (float)hr[t * 128 + lane] * W2[t][lane] +
                (float)hr[t * 128 + 64 + lane] * W2[t][64 + lane];
    for (int msk = 1; msk < 64; msk <<= 1) acc += __shfl_xor(acc, msk);
    outs[t] = acc;
  }
  if (lane == 0) {
    float xn = outs[0] + nb2[0];
    float n = (xn > 20.f) ? xn : log1pf(__expf(xn));
    float mu = 1.f / (1.f + __expf(-(outs[1] + mb2[0])));
    float delta = fmaxf(outs[2] + db2[0], 0.f);
    float surv = logf(n + 1e-8f) + logf(mu + 1e-8f) - delta;
    biasMain[row] = 0.1f * LOG2E * surv + maskBias[row];
  }
}

extern "C" void kernel_launch(void* const* d_in, const int* in_sizes, int n_in,
                              void* d_out, int out_size, void* d_ws, size_t ws_size,
                              hipStream_t stream) {
  const int B = 2, S = 2048, H = 768, I = 256;
  const int NH = 12, SNH = 4;
  const int M = B * S;  // 4096
  const int NF = 2560;
  const float SC = 0.125f * LOG2E;

  const float* x = (const float*)d_in[0];
  const int* mask = (const int*)d_in[1];
  const float* qw = (const float*)d_in[2];
  const float* qb = (const float*)d_in[3];
  const float* kw = (const float*)d_in[4];
  const float* kb = (const float*)d_in[5];
  const float* vw = (const float*)d_in[6];
  const float* vb = (const float*)d_in[7];
  const float* ow = (const float*)d_in[8];
  const float* ob = (const float*)d_in[9];
  const float* sp_w = (const float*)d_in[10];
  const float* sp_b = (const float*)d_in[11];
  const float* sa_in_w = (const float*)d_in[12];
  const float* sa_in_b = (const float*)d_in[13];
  const float* sa_out_w = (const float*)d_in[14];
  const float* sa_out_b = (const float*)d_in[15];
  const float* nw1 = (const float*)d_in[16];
  const float* nb1 = (const float*)d_in[17];
  const float* nw2 = (const float*)d_in[18];
  const float* nb2 = (const float*)d_in[19];
  const float* mw1 = (const float*)d_in[20];
  const float* mb1 = (const float*)d_in[21];
  const float* mw2 = (const float*)d_in[22];
  const float* mb2 = (const float*)d_in[23];
  const float* dw1 = (const float*)d_in[24];
  const float* db1 = (const float*)d_in[25];
  const float* dw2 = (const float*)d_in[26];
  const float* db2 = (const float*)d_in[27];

  char* ws = (char*)d_ws;
  size_t off = 0;
  auto alloc = [&](size_t bytes) -> void* {
    void* p = ws + off;
    off += (bytes + 255) & ~(size_t)255;
    return p;
  };

  // persistent
  bf16* xb = (bf16*)alloc((size_t)M * H * 2);
  bf16* wfused = (bf16*)alloc((size_t)NF * H * 2);
  float* bfused = (float*)alloc((size_t)NF * 4);
  bf16* wob = (bf16*)alloc((size_t)H * H * 2);
  bf16* sainb = (bf16*)alloc((size_t)(3 * I) * I * 2);
  bf16* saoutb = (bf16*)alloc((size_t)I * I * 2);
  bf16* w1pack = (bf16*)alloc((size_t)384 * 256 * 2);
  float* b1pack = (float*)alloc((size_t)384 * 4);
  float* maskBias = (float*)alloc((size_t)M * 4);
  float* biasMain = (float*)alloc((size_t)M * 4);
  bf16* Cfused = (bf16*)alloc((size_t)M * NF * 2);

  const int SPM = 2, SPS = 4;
  size_t offMark = off;
  // phase A (scorer)
  bf16* qkv_s = (bf16*)alloc((size_t)M * (3 * I) * 2);
  bf16* vt_s = (bf16*)alloc((size_t)B * SNH * 64 * S * 2);
  bf16* attn_s = (bf16*)alloc((size_t)M * I * 2);
  bf16* h1 = (bf16*)alloc((size_t)M * I * 2);
  bf16* hid = (bf16*)alloc((size_t)M * 384 * 2);
  bf16* Opart_s = (bf16*)alloc((size_t)SPS * B * SNH * S * 64 * 2);
  float* L_s = (float*)alloc((size_t)SPS * B * SNH * S * 4);
  size_t endA = off;
  // phase B (main) overlays phase A
  off = offMark;
  bf16* vt_m = (bf16*)alloc((size_t)B * NH * 64 * S * 2);
  bf16* attn_m = (bf16*)alloc((size_t)M * H * 2);
  bf16* Opart_m = (bf16*)alloc((size_t)SPM * B * NH * S * 64 * 2);
  float* L_m = (float*)alloc((size_t)SPM * B * NH * S * 4);
  size_t endB = off;
  size_t need = endA > endB ? endA : endB;
  bool split_ok = ws_size >= need;
  (void)in_sizes; (void)n_in; (void)out_size;

  pack_all<<<5926, 256, 0, stream>>>(x, qw, kw, vw, ow, sp_w, sa_in_w, sa_out_w, nw1, mw1, dw1,
                                     sp_b, qb, kb, vb, nb1, mb1, db1, mask,
                                     xb, wfused, wob, sainb, saoutb, w1pack, bfused, b1pack,
                                     maskBias);

  // fused front GEMM: Cfused = xb @ [sp_w; qw; kw; vw]^T + bfused
  gemm_big<0><<<(M / 128) * (NF / 128), 256, 0, stream>>>(xb, wfused, bfused, Cfused, NF,
                                                          NF / 128, H);

  // ---- scorer branch (h0 = Cfused[:, 0:256], lda=NF) ----
  gemm_nt<0, 0><<<(M / 64) * ((3 * I) / 64), 256, 0, stream>>>(Cfused, NF, sainb, I, sa_in_b,
                                                               qkv_s, 3 * I, (3 * I) / 64, I);
  vtrans<<<B * SNH * (S / 64), 256, 0, stream>>>(qkv_s, 3 * I, 2 * I, vt_s, SNH, S);
  if (split_ok) {
    flash12_k<SPS, 1><<<SPS * B * SNH * (S / 128), 256, 0, stream>>>(
        qkv_s, qkv_s + I, 3 * I, vt_s, maskBias, nullptr, 0, Opart_s, L_s, SNH, S, SC, B);
    flash_comb<<<(B * SNH * S * 16) / 256, 256, 0, stream>>>(Opart_s, L_s, attn_s, I, SNH, S,
                                                             B, SPS);
  } else {
    flash12_k<1, 0><<<B * SNH * (S / 128), 256, 0, stream>>>(
        qkv_s, qkv_s + I, 3 * I, vt_s, maskBias, attn_s, I, nullptr, nullptr, SNH, S, SC, B);
  }
  gemm_nt<0, 0><<<(M / 64) * (I / 64), 256, 0, stream>>>(attn_s, I, saoutb, I, sa_out_b, h1, I,
                                                         I / 64, I);
  gemm_nt<0, 1><<<(M / 64) * (384 / 64), 256, 0, stream>>>(h1, I, w1pack, I, b1pack, hid, 384,
                                                           384 / 64, I);
  surv_k<<<M / 4, 256, 0, stream>>>(hid, nw2, nb2, mw2, mb2, dw2, db2, maskBias, biasMain);

  // ---- main branch (Q/K/V = Cfused cols 256/1024/1792, rs=NF) ----
  vtrans<<<B * NH * (S / 64), 256, 0, stream>>>(Cfused, NF, 1792, vt_m, NH, S);
  if (split_ok) {
    flash12_k<SPM, 1><<<SPM * B * NH * (S / 128), 256, 0, stream>>>(
        Cfused + 256, Cfused + 1024, NF, vt_m, biasMain, nullptr, 0, Opart_m, L_m, NH, S, SC,
        B);
    flash_comb<<<(B * NH * S * 16) / 256, 256, 0, stream>>>(Opart_m, L_m, attn_m, H, NH, S, B,
                                                            SPM);
  } else {
    flash12_k<1, 0><<<B * NH * (S / 128), 256, 0, stream>>>(
        Cfused + 256, Cfused + 1024, NF, vt_m, biasMain, attn_m, H, nullptr, nullptr, NH, S,
        SC, B);
  }
  gemm_big<1><<<(M / 128) * (H / 128), 256, 0, stream>>>(attn_m, wob, ob, d_out, H,
                                                         H / 128, H);
}